// Round 1
// baseline (982.644 us; speedup 1.0000x reference)
//
#include <hip/hip_runtime.h>
#include <stdint.h>
#include <stddef.h>

#define N_CHEM 200000
#define N_GENE 20000
#define N_EDGES 1000000
#define IN_D 128
#define HID_D 256
#define OUT_D 128

// ---------------- CSR build ----------------

__global__ void count_kernel(const int* __restrict__ dst, int* __restrict__ cnt, int n) {
    int i = blockIdx.x * blockDim.x + threadIdx.x;
    if (i < n) atomicAdd(&cnt[dst[i]], 1);
}

// Single-block exclusive scan: each thread owns a contiguous chunk.
__global__ void scan_kernel(const int* __restrict__ cnt, int* __restrict__ indptr, int n) {
    __shared__ int sm[1024];
    int tid = threadIdx.x;
    int C = (n + 1023) >> 10;
    int lo = tid * C;
    int hi = lo + C; if (hi > n) hi = n;
    int s = 0;
    for (int i = lo; i < hi; ++i) s += cnt[i];
    sm[tid] = s;
    __syncthreads();
    for (int off = 1; off < 1024; off <<= 1) {
        int t = (tid >= off) ? sm[tid - off] : 0;
        __syncthreads();
        sm[tid] += t;
        __syncthreads();
    }
    int run = sm[tid] - s;   // exclusive prefix of this thread's chunk
    for (int i = lo; i < hi; ++i) { indptr[i] = run; run += cnt[i]; }
    if (tid == 1023) indptr[n] = sm[1023];
}

__global__ void fill_kernel(const int* __restrict__ src, const int* __restrict__ dst,
                            const int* __restrict__ indptr, int* __restrict__ cur,
                            int* __restrict__ esrc, int n) {
    int i = blockIdx.x * blockDim.x + threadIdx.x;
    if (i < n) {
        int d = dst[i];
        int p = indptr[d] + atomicAdd(&cur[d], 1);
        esrc[p] = src[i];
    }
}

// ---------------- gather-mean (segment mean, gather formulation) ----------------
// One 128-thread subgroup per destination node; 4 nodes per 512-thread block.
// Coalesced 512B row loads; zero-in-degree nodes get 0 (matches DGL fn.mean).

__global__ void gather_mean_kernel(const float* __restrict__ table,
                                   const int* __restrict__ indptr,
                                   const int* __restrict__ esrc,
                                   float* __restrict__ out, int n) {
    int col  = threadIdx.x & 127;
    int node = blockIdx.x * 4 + (threadIdx.x >> 7);
    if (node >= n) return;
    int s = indptr[node], e = indptr[node + 1];
    float acc = 0.f;
    int j = s;
    for (; j + 4 <= e; j += 4) {
        int s0 = esrc[j], s1 = esrc[j + 1], s2 = esrc[j + 2], s3 = esrc[j + 3];
        float v0 = table[(size_t)s0 * 128 + col];
        float v1 = table[(size_t)s1 * 128 + col];
        float v2 = table[(size_t)s2 * 128 + col];
        float v3 = table[(size_t)s3 * 128 + col];
        acc += (v0 + v1) + (v2 + v3);
    }
    for (; j < e; ++j) acc += table[(size_t)esrc[j] * 128 + col];
    int deg = e - s;
    out[(size_t)node * 128 + col] = (deg > 0) ? acc / (float)deg : 0.f;
}

// ---------------- f32 VALU GEMM: C[M,N] = A[M,K] @ W[K,N] + bias (+mask/leaky) ----
// 64x64 block tile, 256 threads, 4x4 register tile, 64-wide K tiles in LDS.
// As padded to stride 68 -> a-reads are 2-way bank aliased (free); Ws reads 2-way (free).

template<int K, int N, bool MASK_LEAKY>
__global__ __launch_bounds__(256) void gemm_kernel(const float* __restrict__ A,
                                                   const float* __restrict__ W,
                                                   const float* __restrict__ bias,
                                                   const int* __restrict__ indptr,
                                                   float* __restrict__ C, int M) {
    __shared__ float As[64 * 68];
    __shared__ float Ws[64 * 64];
    const int tid = threadIdx.x;
    const int tx = tid & 15, ty = tid >> 4;
    const int m0 = blockIdx.x * 64;
    const int n0 = blockIdx.y * 64;
    const int r0 = ty << 2, c0 = tx << 2;
    float acc[4][4] = {};

    for (int kt = 0; kt < K; kt += 64) {
        // stage A tile (64 rows x 64 k), zero-pad OOB rows
        #pragma unroll
        for (int q = 0; q < 4; ++q) {
            int idx = tid + q * 256;          // 0..1023
            int row = idx >> 4;               // 64 rows
            int c4  = (idx & 15) << 2;        // 16 float4 per row
            float4 v = make_float4(0.f, 0.f, 0.f, 0.f);
            if (m0 + row < M)
                v = *(const float4*)&A[(size_t)(m0 + row) * K + kt + c4];
            *(float4*)&As[row * 68 + c4] = v;
        }
        // stage W tile (64 k x 64 n)
        #pragma unroll
        for (int q = 0; q < 4; ++q) {
            int idx = tid + q * 256;
            int k   = idx >> 4;
            int c4  = (idx & 15) << 2;
            *(float4*)&Ws[(k << 6) + c4] =
                *(const float4*)&W[(size_t)(kt + k) * N + n0 + c4];
        }
        __syncthreads();

        #pragma unroll 4
        for (int k = 0; k < 64; k += 4) {
            float a[4][4];
            #pragma unroll
            for (int r = 0; r < 4; ++r) {
                float4 v = *(const float4*)&As[(r0 + r) * 68 + k];
                a[r][0] = v.x; a[r][1] = v.y; a[r][2] = v.z; a[r][3] = v.w;
            }
            #pragma unroll
            for (int kk = 0; kk < 4; ++kk) {
                float4 w = *(const float4*)&Ws[((k + kk) << 6) + c0];
                #pragma unroll
                for (int r = 0; r < 4; ++r) {
                    acc[r][0] = fmaf(a[r][kk], w.x, acc[r][0]);
                    acc[r][1] = fmaf(a[r][kk], w.y, acc[r][1]);
                    acc[r][2] = fmaf(a[r][kk], w.z, acc[r][2]);
                    acc[r][3] = fmaf(a[r][kk], w.w, acc[r][3]);
                }
            }
        }
        __syncthreads();
    }

    // epilogue
    float4 b = *(const float4*)&bias[n0 + c0];
    #pragma unroll
    for (int r = 0; r < 4; ++r) {
        int row = m0 + r0 + r;
        if (row < M) {
            float4 v;
            v.x = acc[r][0] + b.x; v.y = acc[r][1] + b.y;
            v.z = acc[r][2] + b.z; v.w = acc[r][3] + b.w;
            if (MASK_LEAKY) {
                int deg = indptr[row + 1] - indptr[row];
                if (deg == 0) {
                    v = make_float4(0.f, 0.f, 0.f, 0.f);
                } else {
                    v.x = v.x > 0.f ? v.x : 0.01f * v.x;
                    v.y = v.y > 0.f ? v.y : 0.01f * v.y;
                    v.z = v.z > 0.f ? v.z : 0.01f * v.z;
                    v.w = v.w > 0.f ? v.w : 0.01f * v.w;
                }
            }
            *(float4*)&C[(size_t)row * N + n0 + c0] = v;
        }
    }
}

// ---------------- launch ----------------

extern "C" void kernel_launch(void* const* d_in, const int* in_sizes, int n_in,
                              void* d_out, int out_size, void* d_ws, size_t ws_size,
                              hipStream_t stream) {
    const int*   src_cg     = (const int*)d_in[0];
    const int*   dst_cg     = (const int*)d_in[1];
    const int*   src_gc     = (const int*)d_in[2];
    const int*   dst_gc     = (const int*)d_in[3];
    const float* embed_chem = (const float*)d_in[4];
    // d_in[5] embed_gene, d_in[8] W1_gc, d_in[9] b1_gc, d_in[10] W2_cg, d_in[11] b2_cg: dead code
    const float* W1_cg = (const float*)d_in[6];
    const float* b1_cg = (const float*)d_in[7];
    const float* W2_gc = (const float*)d_in[12];
    const float* b2_gc = (const float*)d_in[13];
    float* out = (float*)d_out;

    // workspace layout (ints, then 16B-aligned float buffers)
    int* ws_i = (int*)d_ws;
    size_t off = 0;
    int* cnt1 = ws_i + off; off += N_GENE;
    int* cur1 = ws_i + off; off += N_GENE;
    int* cnt2 = ws_i + off; off += N_CHEM;
    int* cur2 = ws_i + off; off += N_CHEM;
    size_t zero_ints = off;                       // [cnt1,cur1,cnt2,cur2] need zeroing
    int* indptr1 = ws_i + off; off += N_GENE + 1; off = (off + 3) & ~(size_t)3;
    int* indptr2 = ws_i + off; off += N_CHEM + 1; off = (off + 3) & ~(size_t)3;
    int* esrc1   = ws_i + off; off += N_EDGES;
    int* esrc2   = ws_i + off; off += N_EDGES;
    float* agg1   = (float*)(ws_i + off); off += (size_t)N_GENE * IN_D;
    float* h_gene = (float*)(ws_i + off); off += (size_t)N_GENE * HID_D;
    float* Wh2    = (float*)(ws_i + off); off += (size_t)N_GENE * OUT_D;

    hipMemsetAsync(ws_i, 0, zero_ints * sizeof(int), stream);

    const int eb = 256, eg = (N_EDGES + eb - 1) / eb;
    count_kernel<<<eg, eb, 0, stream>>>(dst_cg, cnt1, N_EDGES);
    count_kernel<<<eg, eb, 0, stream>>>(dst_gc, cnt2, N_EDGES);
    scan_kernel<<<1, 1024, 0, stream>>>(cnt1, indptr1, N_GENE);
    scan_kernel<<<1, 1024, 0, stream>>>(cnt2, indptr2, N_CHEM);
    fill_kernel<<<eg, eb, 0, stream>>>(src_cg, dst_cg, indptr1, cur1, esrc1, N_EDGES);
    fill_kernel<<<eg, eb, 0, stream>>>(src_gc, dst_gc, indptr2, cur2, esrc2, N_EDGES);

    // layer 1: aggregate raw embeddings (mean is linear; project after)
    gather_mean_kernel<<<(N_GENE + 3) / 4, 512, 0, stream>>>(embed_chem, indptr1, esrc1, agg1, N_GENE);
    // h_gene = deg>0 ? leaky(agg1 @ W1_cg + b1_cg) : 0
    {
        dim3 g((N_GENE + 63) / 64, HID_D / 64), blk(256);
        gemm_kernel<IN_D, HID_D, true><<<g, blk, 0, stream>>>(agg1, W1_cg, b1_cg, indptr1, h_gene, N_GENE);
    }
    // layer 2: project gene features first (256 -> 128), bias for ALL rows
    {
        dim3 g((N_GENE + 63) / 64, OUT_D / 64), blk(256);
        gemm_kernel<HID_D, OUT_D, false><<<g, blk, 0, stream>>>(h_gene, W2_gc, b2_gc, nullptr, Wh2, N_GENE);
    }
    // out = seg_mean(Wh2[src_gc], dst_gc, N_CHEM)
    gather_mean_kernel<<<(N_CHEM + 3) / 4, 512, 0, stream>>>(Wh2, indptr2, esrc2, out, N_CHEM);
}

// Round 2
// 664.486 us; speedup vs baseline: 1.4788x; 1.4788x over previous
//
#include <hip/hip_runtime.h>
#include <stdint.h>
#include <stddef.h>

#define N_CHEM 200000
#define N_GENE 20000
#define N_EDGES 1000000
#define IN_D 128
#define HID_D 256
#define OUT_D 128

// ---------------- CSR build ----------------

__global__ void count_kernel(const int* __restrict__ dst, int* __restrict__ cnt, int n) {
    int i = blockIdx.x * blockDim.x + threadIdx.x;
    if (i < n) atomicAdd(&cnt[dst[i]], 1);
}

// ---------------- 3-phase device-wide exclusive scan (1024 elems / block) ----

__global__ void block_sum_kernel(const int* __restrict__ cnt, int* __restrict__ bsum, int n) {
    __shared__ int sm[256];
    int tid = threadIdx.x;
    int base = blockIdx.x * 1024 + tid * 4;
    int s = 0;
    if (base + 3 < n) {
        int4 v = *(const int4*)&cnt[base];
        s = v.x + v.y + v.z + v.w;
    } else {
        for (int i = 0; i < 4; ++i) if (base + i < n) s += cnt[base + i];
    }
    sm[tid] = s;
    __syncthreads();
    for (int off = 128; off > 0; off >>= 1) {
        if (tid < off) sm[tid] += sm[tid + off];
        __syncthreads();
    }
    if (tid == 0) bsum[blockIdx.x] = sm[0];
}

__global__ void scan_bsum_kernel(int* __restrict__ bsum, int nb) {
    __shared__ int sm[1024];
    int tid = threadIdx.x;
    int v = (tid < nb) ? bsum[tid] : 0;
    sm[tid] = v;
    __syncthreads();
    for (int off = 1; off < 1024; off <<= 1) {
        int t = (tid >= off) ? sm[tid - off] : 0;
        __syncthreads();
        sm[tid] += t;
        __syncthreads();
    }
    if (tid < nb) bsum[tid] = sm[tid] - v;   // exclusive
}

__global__ void scan_fill_kernel(const int* __restrict__ cnt, const int* __restrict__ bsum,
                                 int* __restrict__ indptr, int n) {
    __shared__ int sm[256];
    int tid = threadIdx.x;
    int base = blockIdx.x * 1024 + tid * 4;
    int v[4]; int s = 0;
    #pragma unroll
    for (int i = 0; i < 4; ++i) { v[i] = (base + i < n) ? cnt[base + i] : 0; s += v[i]; }
    sm[tid] = s;
    __syncthreads();
    for (int off = 1; off < 256; off <<= 1) {
        int t = (tid >= off) ? sm[tid - off] : 0;
        __syncthreads();
        sm[tid] += t;
        __syncthreads();
    }
    int prefix = bsum[blockIdx.x] + sm[tid] - s;   // exclusive prefix for this thread
    #pragma unroll
    for (int i = 0; i < 4; ++i) {
        if (base + i < n) indptr[base + i] = prefix;
        prefix += v[i];
        if (base + i == n - 1) indptr[n] = prefix;
    }
}

__global__ void fill_kernel(const int* __restrict__ src, const int* __restrict__ dst,
                            const int* __restrict__ indptr, int* __restrict__ cur,
                            int* __restrict__ esrc, int n) {
    int i = blockIdx.x * blockDim.x + threadIdx.x;
    if (i < n) {
        int d = dst[i];
        int p = indptr[d] + atomicAdd(&cur[d], 1);
        esrc[p] = src[i];
    }
}

// ---------------- gather-mean (segment mean, gather formulation) ----------------
// One 128-thread subgroup per destination node; 4 nodes per 512-thread block.

__global__ void gather_mean_kernel(const float* __restrict__ table,
                                   const int* __restrict__ indptr,
                                   const int* __restrict__ esrc,
                                   float* __restrict__ out, int n) {
    int col  = threadIdx.x & 127;
    int node = blockIdx.x * 4 + (threadIdx.x >> 7);
    if (node >= n) return;
    int s = indptr[node], e = indptr[node + 1];
    float acc = 0.f;
    int j = s;
    for (; j + 4 <= e; j += 4) {
        int s0 = esrc[j], s1 = esrc[j + 1], s2 = esrc[j + 2], s3 = esrc[j + 3];
        float v0 = table[(size_t)s0 * 128 + col];
        float v1 = table[(size_t)s1 * 128 + col];
        float v2 = table[(size_t)s2 * 128 + col];
        float v3 = table[(size_t)s3 * 128 + col];
        acc += (v0 + v1) + (v2 + v3);
    }
    for (; j < e; ++j) acc += table[(size_t)esrc[j] * 128 + col];
    int deg = e - s;
    out[(size_t)node * 128 + col] = (deg > 0) ? acc / (float)deg : 0.f;
}

// ---------------- f32 VALU GEMM: C[M,N] = A[M,K] @ W[K,N] + bias (+mask/leaky) ----
// 64x64 block tile, 256 threads, 4x4 register tile, 64-wide K tiles in LDS.

template<int K, int N, bool MASK_LEAKY>
__global__ __launch_bounds__(256) void gemm_kernel(const float* __restrict__ A,
                                                   const float* __restrict__ W,
                                                   const float* __restrict__ bias,
                                                   const int* __restrict__ indptr,
                                                   float* __restrict__ C, int M) {
    __shared__ float As[64 * 68];
    __shared__ float Ws[64 * 64];
    const int tid = threadIdx.x;
    const int tx = tid & 15, ty = tid >> 4;
    const int m0 = blockIdx.x * 64;
    const int n0 = blockIdx.y * 64;
    const int r0 = ty << 2, c0 = tx << 2;
    float acc[4][4] = {};

    for (int kt = 0; kt < K; kt += 64) {
        #pragma unroll
        for (int q = 0; q < 4; ++q) {
            int idx = tid + q * 256;
            int row = idx >> 4;
            int c4  = (idx & 15) << 2;
            float4 v = make_float4(0.f, 0.f, 0.f, 0.f);
            if (m0 + row < M)
                v = *(const float4*)&A[(size_t)(m0 + row) * K + kt + c4];
            *(float4*)&As[row * 68 + c4] = v;
        }
        #pragma unroll
        for (int q = 0; q < 4; ++q) {
            int idx = tid + q * 256;
            int k   = idx >> 4;
            int c4  = (idx & 15) << 2;
            *(float4*)&Ws[(k << 6) + c4] =
                *(const float4*)&W[(size_t)(kt + k) * N + n0 + c4];
        }
        __syncthreads();

        #pragma unroll 4
        for (int k = 0; k < 64; k += 4) {
            float a[4][4];
            #pragma unroll
            for (int r = 0; r < 4; ++r) {
                float4 v = *(const float4*)&As[(r0 + r) * 68 + k];
                a[r][0] = v.x; a[r][1] = v.y; a[r][2] = v.z; a[r][3] = v.w;
            }
            #pragma unroll
            for (int kk = 0; kk < 4; ++kk) {
                float4 w = *(const float4*)&Ws[((k + kk) << 6) + c0];
                #pragma unroll
                for (int r = 0; r < 4; ++r) {
                    acc[r][0] = fmaf(a[r][kk], w.x, acc[r][0]);
                    acc[r][1] = fmaf(a[r][kk], w.y, acc[r][1]);
                    acc[r][2] = fmaf(a[r][kk], w.z, acc[r][2]);
                    acc[r][3] = fmaf(a[r][kk], w.w, acc[r][3]);
                }
            }
        }
        __syncthreads();
    }

    float4 b = *(const float4*)&bias[n0 + c0];
    #pragma unroll
    for (int r = 0; r < 4; ++r) {
        int row = m0 + r0 + r;
        if (row < M) {
            float4 v;
            v.x = acc[r][0] + b.x; v.y = acc[r][1] + b.y;
            v.z = acc[r][2] + b.z; v.w = acc[r][3] + b.w;
            if (MASK_LEAKY) {
                int deg = indptr[row + 1] - indptr[row];
                if (deg == 0) {
                    v = make_float4(0.f, 0.f, 0.f, 0.f);
                } else {
                    v.x = v.x > 0.f ? v.x : 0.01f * v.x;
                    v.y = v.y > 0.f ? v.y : 0.01f * v.y;
                    v.z = v.z > 0.f ? v.z : 0.01f * v.z;
                    v.w = v.w > 0.f ? v.w : 0.01f * v.w;
                }
            }
            *(float4*)&C[(size_t)row * N + n0 + c0] = v;
        }
    }
}

// ---------------- launch ----------------

extern "C" void kernel_launch(void* const* d_in, const int* in_sizes, int n_in,
                              void* d_out, int out_size, void* d_ws, size_t ws_size,
                              hipStream_t stream) {
    const int*   src_cg     = (const int*)d_in[0];
    const int*   dst_cg     = (const int*)d_in[1];
    const int*   src_gc     = (const int*)d_in[2];
    const int*   dst_gc     = (const int*)d_in[3];
    const float* embed_chem = (const float*)d_in[4];
    const float* W1_cg = (const float*)d_in[6];
    const float* b1_cg = (const float*)d_in[7];
    const float* W2_gc = (const float*)d_in[12];
    const float* b2_gc = (const float*)d_in[13];
    float* out = (float*)d_out;

    // workspace layout
    int* ws_i = (int*)d_ws;
    size_t off = 0;
    int* cnt1 = ws_i + off; off += N_GENE;
    int* cur1 = ws_i + off; off += N_GENE;
    int* cnt2 = ws_i + off; off += N_CHEM;
    int* cur2 = ws_i + off; off += N_CHEM;
    size_t zero_ints = off;
    int* bsum1   = ws_i + off; off += 1024;
    int* bsum2   = ws_i + off; off += 1024;
    int* indptr1 = ws_i + off; off += N_GENE + 1; off = (off + 3) & ~(size_t)3;
    int* indptr2 = ws_i + off; off += N_CHEM + 1; off = (off + 3) & ~(size_t)3;
    int* esrc1   = ws_i + off; off += N_EDGES;
    int* esrc2   = ws_i + off; off += N_EDGES;
    float* agg1   = (float*)(ws_i + off); off += (size_t)N_GENE * IN_D;
    float* h_gene = (float*)(ws_i + off); off += (size_t)N_GENE * HID_D;
    float* Wh2    = (float*)(ws_i + off); off += (size_t)N_GENE * OUT_D;

    hipMemsetAsync(ws_i, 0, zero_ints * sizeof(int), stream);

    const int eb = 256, eg = (N_EDGES + eb - 1) / eb;
    count_kernel<<<eg, eb, 0, stream>>>(dst_cg, cnt1, N_EDGES);
    count_kernel<<<eg, eb, 0, stream>>>(dst_gc, cnt2, N_EDGES);

    const int nb1 = (N_GENE + 1023) / 1024;   // 20
    const int nb2 = (N_CHEM + 1023) / 1024;   // 196
    block_sum_kernel<<<nb1, 256, 0, stream>>>(cnt1, bsum1, N_GENE);
    block_sum_kernel<<<nb2, 256, 0, stream>>>(cnt2, bsum2, N_CHEM);
    scan_bsum_kernel<<<1, 1024, 0, stream>>>(bsum1, nb1);
    scan_bsum_kernel<<<1, 1024, 0, stream>>>(bsum2, nb2);
    scan_fill_kernel<<<nb1, 256, 0, stream>>>(cnt1, bsum1, indptr1, N_GENE);
    scan_fill_kernel<<<nb2, 256, 0, stream>>>(cnt2, bsum2, indptr2, N_CHEM);

    fill_kernel<<<eg, eb, 0, stream>>>(src_cg, dst_cg, indptr1, cur1, esrc1, N_EDGES);
    fill_kernel<<<eg, eb, 0, stream>>>(src_gc, dst_gc, indptr2, cur2, esrc2, N_EDGES);

    // layer 1: aggregate raw embeddings (mean is linear; project after)
    gather_mean_kernel<<<(N_GENE + 3) / 4, 512, 0, stream>>>(embed_chem, indptr1, esrc1, agg1, N_GENE);
    {
        dim3 g((N_GENE + 63) / 64, HID_D / 64), blk(256);
        gemm_kernel<IN_D, HID_D, true><<<g, blk, 0, stream>>>(agg1, W1_cg, b1_cg, indptr1, h_gene, N_GENE);
    }
    {
        dim3 g((N_GENE + 63) / 64, OUT_D / 64), blk(256);
        gemm_kernel<HID_D, OUT_D, false><<<g, blk, 0, stream>>>(h_gene, W2_gc, b2_gc, nullptr, Wh2, N_GENE);
    }
    gather_mean_kernel<<<(N_CHEM + 3) / 4, 512, 0, stream>>>(Wh2, indptr2, esrc2, out, N_CHEM);
}

// Round 4
// 583.625 us; speedup vs baseline: 1.6837x; 1.1386x over previous
//
#include <hip/hip_runtime.h>
#include <stdint.h>
#include <stddef.h>

#define N_CHEM 200000
#define N_GENE 20000
#define N_EDGES 1000000
#define IN_D 128
#define HID_D 256
#define OUT_D 128

typedef float nfloat4 __attribute__((ext_vector_type(4)));   // native vec for NT store

// ---------------- CSR build ----------------

__global__ void count_kernel(const int* __restrict__ dst, int* __restrict__ cnt, int n) {
    int i = blockIdx.x * blockDim.x + threadIdx.x;
    if (i < n) atomicAdd(&cnt[dst[i]], 1);
}

// ---------------- 3-phase device-wide exclusive scan (1024 elems / block) ----

__global__ void block_sum_kernel(const int* __restrict__ cnt, int* __restrict__ bsum, int n) {
    __shared__ int sm[256];
    int tid = threadIdx.x;
    int base = blockIdx.x * 1024 + tid * 4;
    int s = 0;
    if (base + 3 < n) {
        int4 v = *(const int4*)&cnt[base];
        s = v.x + v.y + v.z + v.w;
    } else {
        for (int i = 0; i < 4; ++i) if (base + i < n) s += cnt[base + i];
    }
    sm[tid] = s;
    __syncthreads();
    for (int off = 128; off > 0; off >>= 1) {
        if (tid < off) sm[tid] += sm[tid + off];
        __syncthreads();
    }
    if (tid == 0) bsum[blockIdx.x] = sm[0];
}

__global__ void scan_bsum_kernel(int* __restrict__ bsum, int nb) {
    __shared__ int sm[1024];
    int tid = threadIdx.x;
    int v = (tid < nb) ? bsum[tid] : 0;
    sm[tid] = v;
    __syncthreads();
    for (int off = 1; off < 1024; off <<= 1) {
        int t = (tid >= off) ? sm[tid - off] : 0;
        __syncthreads();
        sm[tid] += t;
        __syncthreads();
    }
    if (tid < nb) bsum[tid] = sm[tid] - v;   // exclusive
}

__global__ void scan_fill_kernel(const int* __restrict__ cnt, const int* __restrict__ bsum,
                                 int* __restrict__ indptr, int n) {
    __shared__ int sm[256];
    int tid = threadIdx.x;
    int base = blockIdx.x * 1024 + tid * 4;
    int v[4]; int s = 0;
    #pragma unroll
    for (int i = 0; i < 4; ++i) { v[i] = (base + i < n) ? cnt[base + i] : 0; s += v[i]; }
    sm[tid] = s;
    __syncthreads();
    for (int off = 1; off < 256; off <<= 1) {
        int t = (tid >= off) ? sm[tid - off] : 0;
        __syncthreads();
        sm[tid] += t;
        __syncthreads();
    }
    int prefix = bsum[blockIdx.x] + sm[tid] - s;
    #pragma unroll
    for (int i = 0; i < 4; ++i) {
        if (base + i < n) indptr[base + i] = prefix;
        prefix += v[i];
        if (base + i == n - 1) indptr[n] = prefix;
    }
}

__global__ void fill_kernel(const int* __restrict__ src, const int* __restrict__ dst,
                            const int* __restrict__ indptr, int* __restrict__ cur,
                            int* __restrict__ esrc, int n) {
    int i = blockIdx.x * blockDim.x + threadIdx.x;
    if (i < n) {
        int d = dst[i];
        int p = indptr[d] + atomicAdd(&cur[d], 1);
        esrc[p] = src[i];
    }
}

// ---------------- gather-mean: 32 lanes/node, float4 loads -------------------
// Each lane owns 4 contiguous cols (16B). 8 nodes per 256-thread block.
// Edge unroll x4 -> 4 independent dwordx4 loads (64B) in flight per lane.
// NT: nontemporal output store (don't let the 102MB out evict the gather table).

template<bool NT>
__global__ __launch_bounds__(256) void gather_mean_kernel(const float* __restrict__ table,
                                                          const int* __restrict__ indptr,
                                                          const int* __restrict__ esrc,
                                                          float* __restrict__ out, int n) {
    int lane = threadIdx.x & 31;
    int node = blockIdx.x * 8 + (threadIdx.x >> 5);
    if (node >= n) return;
    int s = indptr[node], e = indptr[node + 1];
    int c = lane << 2;
    float4 acc = make_float4(0.f, 0.f, 0.f, 0.f);
    int j = s;
    for (; j + 4 <= e; j += 4) {
        int s0 = esrc[j], s1 = esrc[j + 1], s2 = esrc[j + 2], s3 = esrc[j + 3];
        float4 v0 = *(const float4*)&table[(size_t)s0 * 128 + c];
        float4 v1 = *(const float4*)&table[(size_t)s1 * 128 + c];
        float4 v2 = *(const float4*)&table[(size_t)s2 * 128 + c];
        float4 v3 = *(const float4*)&table[(size_t)s3 * 128 + c];
        acc.x += (v0.x + v1.x) + (v2.x + v3.x);
        acc.y += (v0.y + v1.y) + (v2.y + v3.y);
        acc.z += (v0.z + v1.z) + (v2.z + v3.z);
        acc.w += (v0.w + v1.w) + (v2.w + v3.w);
    }
    for (; j < e; ++j) {
        float4 v = *(const float4*)&table[(size_t)esrc[j] * 128 + c];
        acc.x += v.x; acc.y += v.y; acc.z += v.z; acc.w += v.w;
    }
    int deg = e - s;
    float inv = (deg > 0) ? 1.f / (float)deg : 0.f;
    acc.x *= inv; acc.y *= inv; acc.z *= inv; acc.w *= inv;
    if (NT) {
        nfloat4 nv = { acc.x, acc.y, acc.z, acc.w };
        __builtin_nontemporal_store(nv, (nfloat4*)&out[(size_t)node * 128 + c]);
    } else {
        *(float4*)&out[(size_t)node * 128 + c] = acc;
    }
}

// ---------------- f32 VALU GEMM: C[M,N] = A[M,K] @ W[K,N] + bias (+mask/leaky) ----

template<int K, int N, bool MASK_LEAKY>
__global__ __launch_bounds__(256) void gemm_kernel(const float* __restrict__ A,
                                                   const float* __restrict__ W,
                                                   const float* __restrict__ bias,
                                                   const int* __restrict__ indptr,
                                                   float* __restrict__ C, int M) {
    __shared__ float As[64 * 68];
    __shared__ float Ws[64 * 64];
    const int tid = threadIdx.x;
    const int tx = tid & 15, ty = tid >> 4;
    const int m0 = blockIdx.x * 64;
    const int n0 = blockIdx.y * 64;
    const int r0 = ty << 2, c0 = tx << 2;
    float acc[4][4] = {};

    for (int kt = 0; kt < K; kt += 64) {
        #pragma unroll
        for (int q = 0; q < 4; ++q) {
            int idx = tid + q * 256;
            int row = idx >> 4;
            int c4  = (idx & 15) << 2;
            float4 v = make_float4(0.f, 0.f, 0.f, 0.f);
            if (m0 + row < M)
                v = *(const float4*)&A[(size_t)(m0 + row) * K + kt + c4];
            *(float4*)&As[row * 68 + c4] = v;
        }
        #pragma unroll
        for (int q = 0; q < 4; ++q) {
            int idx = tid + q * 256;
            int k   = idx >> 4;
            int c4  = (idx & 15) << 2;
            *(float4*)&Ws[(k << 6) + c4] =
                *(const float4*)&W[(size_t)(kt + k) * N + n0 + c4];
        }
        __syncthreads();

        #pragma unroll 4
        for (int k = 0; k < 64; k += 4) {
            float a[4][4];
            #pragma unroll
            for (int r = 0; r < 4; ++r) {
                float4 v = *(const float4*)&As[(r0 + r) * 68 + k];
                a[r][0] = v.x; a[r][1] = v.y; a[r][2] = v.z; a[r][3] = v.w;
            }
            #pragma unroll
            for (int kk = 0; kk < 4; ++kk) {
                float4 w = *(const float4*)&Ws[((k + kk) << 6) + c0];
                #pragma unroll
                for (int r = 0; r < 4; ++r) {
                    acc[r][0] = fmaf(a[r][kk], w.x, acc[r][0]);
                    acc[r][1] = fmaf(a[r][kk], w.y, acc[r][1]);
                    acc[r][2] = fmaf(a[r][kk], w.z, acc[r][2]);
                    acc[r][3] = fmaf(a[r][kk], w.w, acc[r][3]);
                }
            }
        }
        __syncthreads();
    }

    float4 b = *(const float4*)&bias[n0 + c0];
    #pragma unroll
    for (int r = 0; r < 4; ++r) {
        int row = m0 + r0 + r;
        if (row < M) {
            float4 v;
            v.x = acc[r][0] + b.x; v.y = acc[r][1] + b.y;
            v.z = acc[r][2] + b.z; v.w = acc[r][3] + b.w;
            if (MASK_LEAKY) {
                int deg = indptr[row + 1] - indptr[row];
                if (deg == 0) {
                    v = make_float4(0.f, 0.f, 0.f, 0.f);
                } else {
                    v.x = v.x > 0.f ? v.x : 0.01f * v.x;
                    v.y = v.y > 0.f ? v.y : 0.01f * v.y;
                    v.z = v.z > 0.f ? v.z : 0.01f * v.z;
                    v.w = v.w > 0.f ? v.w : 0.01f * v.w;
                }
            }
            *(float4*)&C[(size_t)row * N + n0 + c0] = v;
        }
    }
}

// ---------------- launch ----------------

extern "C" void kernel_launch(void* const* d_in, const int* in_sizes, int n_in,
                              void* d_out, int out_size, void* d_ws, size_t ws_size,
                              hipStream_t stream) {
    const int*   src_cg     = (const int*)d_in[0];
    const int*   dst_cg     = (const int*)d_in[1];
    const int*   src_gc     = (const int*)d_in[2];
    const int*   dst_gc     = (const int*)d_in[3];
    const float* embed_chem = (const float*)d_in[4];
    const float* W1_cg = (const float*)d_in[6];
    const float* b1_cg = (const float*)d_in[7];
    const float* W2_gc = (const float*)d_in[12];
    const float* b2_gc = (const float*)d_in[13];
    float* out = (float*)d_out;

    // workspace layout
    int* ws_i = (int*)d_ws;
    size_t off = 0;
    int* cnt1 = ws_i + off; off += N_GENE;
    int* cur1 = ws_i + off; off += N_GENE;
    int* cnt2 = ws_i + off; off += N_CHEM;
    int* cur2 = ws_i + off; off += N_CHEM;
    size_t zero_ints = off;
    int* bsum1   = ws_i + off; off += 1024;
    int* bsum2   = ws_i + off; off += 1024;
    int* indptr1 = ws_i + off; off += N_GENE + 1; off = (off + 3) & ~(size_t)3;
    int* indptr2 = ws_i + off; off += N_CHEM + 1; off = (off + 3) & ~(size_t)3;
    int* esrc1   = ws_i + off; off += N_EDGES;
    int* esrc2   = ws_i + off; off += N_EDGES;
    float* agg1   = (float*)(ws_i + off); off += (size_t)N_GENE * IN_D;
    float* h_gene = (float*)(ws_i + off); off += (size_t)N_GENE * HID_D;
    float* Wh2    = (float*)(ws_i + off); off += (size_t)N_GENE * OUT_D;

    (void)hipMemsetAsync(ws_i, 0, zero_ints * sizeof(int), stream);

    const int eb = 256, eg = (N_EDGES + eb - 1) / eb;
    count_kernel<<<eg, eb, 0, stream>>>(dst_cg, cnt1, N_EDGES);
    count_kernel<<<eg, eb, 0, stream>>>(dst_gc, cnt2, N_EDGES);

    const int nb1 = (N_GENE + 1023) / 1024;   // 20
    const int nb2 = (N_CHEM + 1023) / 1024;   // 196
    block_sum_kernel<<<nb1, 256, 0, stream>>>(cnt1, bsum1, N_GENE);
    block_sum_kernel<<<nb2, 256, 0, stream>>>(cnt2, bsum2, N_CHEM);
    scan_bsum_kernel<<<1, 1024, 0, stream>>>(bsum1, nb1);
    scan_bsum_kernel<<<1, 1024, 0, stream>>>(bsum2, nb2);
    scan_fill_kernel<<<nb1, 256, 0, stream>>>(cnt1, bsum1, indptr1, N_GENE);
    scan_fill_kernel<<<nb2, 256, 0, stream>>>(cnt2, bsum2, indptr2, N_CHEM);

    fill_kernel<<<eg, eb, 0, stream>>>(src_cg, dst_cg, indptr1, cur1, esrc1, N_EDGES);
    fill_kernel<<<eg, eb, 0, stream>>>(src_gc, dst_gc, indptr2, cur2, esrc2, N_EDGES);

    // layer 1: aggregate raw embeddings (mean is linear; project after)
    gather_mean_kernel<false><<<(N_GENE + 7) / 8, 256, 0, stream>>>(embed_chem, indptr1, esrc1, agg1, N_GENE);
    {
        dim3 g((N_GENE + 63) / 64, HID_D / 64), blk(256);
        gemm_kernel<IN_D, HID_D, true><<<g, blk, 0, stream>>>(agg1, W1_cg, b1_cg, indptr1, h_gene, N_GENE);
    }
    {
        dim3 g((N_GENE + 63) / 64, OUT_D / 64), blk(256);
        gemm_kernel<HID_D, OUT_D, false><<<g, blk, 0, stream>>>(h_gene, W2_gc, b2_gc, nullptr, Wh2, N_GENE);
    }
    gather_mean_kernel<true><<<(N_CHEM + 7) / 8, 256, 0, stream>>>(Wh2, indptr2, esrc2, out, N_CHEM);
}

// Round 5
// 549.263 us; speedup vs baseline: 1.7890x; 1.0626x over previous
//
#include <hip/hip_runtime.h>
#include <stdint.h>
#include <stddef.h>

#define N_CHEM 200000
#define N_GENE 20000
#define N_EDGES 1000000
#define IN_D 128
#define HID_D 256
#define OUT_D 128
#define N_SEG (N_GENE + N_CHEM)          // 220000 concatenated segments

typedef float nfloat4 __attribute__((ext_vector_type(4)));   // native vec for NT store

__device__ inline unsigned bf16rne(float x) {
    unsigned u = __float_as_uint(x);
    return (u + 0x7FFFu + ((u >> 16) & 1u)) >> 16;
}

// ---------------- fused CSR build (both etypes in one segment space) --------

__global__ void count_kernel(const int* __restrict__ dst_cg, const int* __restrict__ dst_gc,
                             int* __restrict__ cnt) {
    int i = blockIdx.x * blockDim.x + threadIdx.x;
    if (i < N_EDGES)            atomicAdd(&cnt[dst_cg[i]], 1);
    else if (i < 2 * N_EDGES)   atomicAdd(&cnt[N_GENE + dst_gc[i - N_EDGES]], 1);
}

__global__ void block_sum_kernel(const int* __restrict__ cnt, int* __restrict__ bsum, int n) {
    __shared__ int sm[256];
    int tid = threadIdx.x;
    int base = blockIdx.x * 1024 + tid * 4;
    int s = 0;
    if (base + 3 < n) {
        int4 v = *(const int4*)&cnt[base];
        s = v.x + v.y + v.z + v.w;
    } else {
        for (int i = 0; i < 4; ++i) if (base + i < n) s += cnt[base + i];
    }
    sm[tid] = s;
    __syncthreads();
    for (int off = 128; off > 0; off >>= 1) {
        if (tid < off) sm[tid] += sm[tid + off];
        __syncthreads();
    }
    if (tid == 0) bsum[blockIdx.x] = sm[0];
}

__global__ void scan_bsum_kernel(int* __restrict__ bsum, int nb) {
    __shared__ int sm[1024];
    int tid = threadIdx.x;
    int v = (tid < nb) ? bsum[tid] : 0;
    sm[tid] = v;
    __syncthreads();
    for (int off = 1; off < 1024; off <<= 1) {
        int t = (tid >= off) ? sm[tid - off] : 0;
        __syncthreads();
        sm[tid] += t;
        __syncthreads();
    }
    if (tid < nb) bsum[tid] = sm[tid] - v;   // exclusive
}

__global__ void scan_fill_kernel(const int* __restrict__ cnt, const int* __restrict__ bsum,
                                 int* __restrict__ indptr, int n) {
    __shared__ int sm[256];
    int tid = threadIdx.x;
    int base = blockIdx.x * 1024 + tid * 4;
    int v[4]; int s = 0;
    #pragma unroll
    for (int i = 0; i < 4; ++i) { v[i] = (base + i < n) ? cnt[base + i] : 0; s += v[i]; }
    sm[tid] = s;
    __syncthreads();
    for (int off = 1; off < 256; off <<= 1) {
        int t = (tid >= off) ? sm[tid - off] : 0;
        __syncthreads();
        sm[tid] += t;
        __syncthreads();
    }
    int prefix = bsum[blockIdx.x] + sm[tid] - s;
    #pragma unroll
    for (int i = 0; i < 4; ++i) {
        if (base + i < n) indptr[base + i] = prefix;
        prefix += v[i];
        if (base + i == n - 1) indptr[n] = prefix;
    }
}

__global__ void fill_kernel(const int* __restrict__ src_cg, const int* __restrict__ dst_cg,
                            const int* __restrict__ src_gc, const int* __restrict__ dst_gc,
                            const int* __restrict__ indptr, int* __restrict__ cur,
                            int* __restrict__ esrc) {
    int i = blockIdx.x * blockDim.x + threadIdx.x;
    int slot, s;
    if (i < N_EDGES)          { slot = dst_cg[i];                    s = src_cg[i]; }
    else if (i < 2 * N_EDGES) { slot = N_GENE + dst_gc[i - N_EDGES]; s = src_gc[i - N_EDGES]; }
    else return;
    int p = indptr[slot] + atomicAdd(&cur[slot], 1);
    esrc[p] = s;
}

// ---------------- f32 -> bf16 table conversion ------------------------------

__global__ void f32_to_bf16_kernel(const float* __restrict__ in,
                                   unsigned short* __restrict__ out, int n4) {
    int i = blockIdx.x * blockDim.x + threadIdx.x;
    if (i >= n4) return;
    float4 v = *(const float4*)&in[(size_t)i * 4];
    uint2 w;
    w.x = bf16rne(v.x) | (bf16rne(v.y) << 16);
    w.y = bf16rne(v.z) | (bf16rne(v.w) << 16);
    *(uint2*)&out[(size_t)i * 4] = w;
}

// ---------------- gather-mean over a bf16 table -----------------------------
// 16 lanes/node, 8 cols/lane -> one dwordx4 (16B) per edge per lane.
// 16 nodes per 256-thread block. f32 accumulate, f32 output.

__device__ inline void acc_u(float* a, uint4 v) {
    a[0] += __uint_as_float(v.x << 16); a[1] += __uint_as_float(v.x & 0xffff0000u);
    a[2] += __uint_as_float(v.y << 16); a[3] += __uint_as_float(v.y & 0xffff0000u);
    a[4] += __uint_as_float(v.z << 16); a[5] += __uint_as_float(v.z & 0xffff0000u);
    a[6] += __uint_as_float(v.w << 16); a[7] += __uint_as_float(v.w & 0xffff0000u);
}

template<bool NT>
__global__ __launch_bounds__(256) void gather_mean_bf16_kernel(
        const unsigned short* __restrict__ table,
        const int* __restrict__ indptr, const int* __restrict__ esrc,
        float* __restrict__ out, int n) {
    int lane = threadIdx.x & 15;
    int node = blockIdx.x * 16 + (threadIdx.x >> 4);
    if (node >= n) return;
    int s = indptr[node], e = indptr[node + 1];
    int c = lane << 3;                       // 8 cols per lane
    float acc[8] = {};
    int j = s;
    for (; j + 4 <= e; j += 4) {
        uint4 v0 = *(const uint4*)&table[(size_t)esrc[j]     * 128 + c];
        uint4 v1 = *(const uint4*)&table[(size_t)esrc[j + 1] * 128 + c];
        uint4 v2 = *(const uint4*)&table[(size_t)esrc[j + 2] * 128 + c];
        uint4 v3 = *(const uint4*)&table[(size_t)esrc[j + 3] * 128 + c];
        acc_u(acc, v0); acc_u(acc, v1); acc_u(acc, v2); acc_u(acc, v3);
    }
    for (; j < e; ++j) {
        uint4 v = *(const uint4*)&table[(size_t)esrc[j] * 128 + c];
        acc_u(acc, v);
    }
    int deg = e - s;
    float inv = (deg > 0) ? 1.f / (float)deg : 0.f;
    #pragma unroll
    for (int q = 0; q < 8; ++q) acc[q] *= inv;
    float* dst = &out[(size_t)node * 128 + c];
    if (NT) {
        nfloat4 a = { acc[0], acc[1], acc[2], acc[3] };
        nfloat4 b = { acc[4], acc[5], acc[6], acc[7] };
        __builtin_nontemporal_store(a, (nfloat4*)dst);
        __builtin_nontemporal_store(b, (nfloat4*)(dst + 4));
    } else {
        *(float4*)dst       = make_float4(acc[0], acc[1], acc[2], acc[3]);
        *(float4*)(dst + 4) = make_float4(acc[4], acc[5], acc[6], acc[7]);
    }
}

// ---------------- gather-mean over an f32 table (ws-fallback path) ----------

__global__ __launch_bounds__(256) void gather_mean_f32_kernel(
        const float* __restrict__ table,
        const int* __restrict__ indptr, const int* __restrict__ esrc,
        float* __restrict__ out, int n) {
    int lane = threadIdx.x & 31;
    int node = blockIdx.x * 8 + (threadIdx.x >> 5);
    if (node >= n) return;
    int s = indptr[node], e = indptr[node + 1];
    int c = lane << 2;
    float4 acc = make_float4(0.f, 0.f, 0.f, 0.f);
    int j = s;
    for (; j + 4 <= e; j += 4) {
        int s0 = esrc[j], s1 = esrc[j + 1], s2 = esrc[j + 2], s3 = esrc[j + 3];
        float4 v0 = *(const float4*)&table[(size_t)s0 * 128 + c];
        float4 v1 = *(const float4*)&table[(size_t)s1 * 128 + c];
        float4 v2 = *(const float4*)&table[(size_t)s2 * 128 + c];
        float4 v3 = *(const float4*)&table[(size_t)s3 * 128 + c];
        acc.x += (v0.x + v1.x) + (v2.x + v3.x);
        acc.y += (v0.y + v1.y) + (v2.y + v3.y);
        acc.z += (v0.z + v1.z) + (v2.z + v3.z);
        acc.w += (v0.w + v1.w) + (v2.w + v3.w);
    }
    for (; j < e; ++j) {
        float4 v = *(const float4*)&table[(size_t)esrc[j] * 128 + c];
        acc.x += v.x; acc.y += v.y; acc.z += v.z; acc.w += v.w;
    }
    int deg = e - s;
    float inv = (deg > 0) ? 1.f / (float)deg : 0.f;
    acc.x *= inv; acc.y *= inv; acc.z *= inv; acc.w *= inv;
    *(float4*)&out[(size_t)node * 128 + c] = acc;
}

// ---------------- f32 VALU GEMM: C[M,N] = A[M,K] @ W[K,N] + bias ------------
// MASK_LEAKY: zero rows with deg==0 else leaky-relu.  BF16_OUT: pack output bf16.

template<int K, int N, bool MASK_LEAKY, bool BF16_OUT>
__global__ __launch_bounds__(256) void gemm_kernel(const float* __restrict__ A,
                                                   const float* __restrict__ W,
                                                   const float* __restrict__ bias,
                                                   const int* __restrict__ indptr,
                                                   void* __restrict__ Cout, int M) {
    __shared__ float As[64 * 68];
    __shared__ float Ws[64 * 64];
    const int tid = threadIdx.x;
    const int tx = tid & 15, ty = tid >> 4;
    const int m0 = blockIdx.x * 64;
    const int n0 = blockIdx.y * 64;
    const int r0 = ty << 2, c0 = tx << 2;
    float acc[4][4] = {};

    for (int kt = 0; kt < K; kt += 64) {
        #pragma unroll
        for (int q = 0; q < 4; ++q) {
            int idx = tid + q * 256;
            int row = idx >> 4;
            int c4  = (idx & 15) << 2;
            float4 v = make_float4(0.f, 0.f, 0.f, 0.f);
            if (m0 + row < M)
                v = *(const float4*)&A[(size_t)(m0 + row) * K + kt + c4];
            *(float4*)&As[row * 68 + c4] = v;
        }
        #pragma unroll
        for (int q = 0; q < 4; ++q) {
            int idx = tid + q * 256;
            int k   = idx >> 4;
            int c4  = (idx & 15) << 2;
            *(float4*)&Ws[(k << 6) + c4] =
                *(const float4*)&W[(size_t)(kt + k) * N + n0 + c4];
        }
        __syncthreads();

        #pragma unroll 4
        for (int k = 0; k < 64; k += 4) {
            float a[4][4];
            #pragma unroll
            for (int r = 0; r < 4; ++r) {
                float4 v = *(const float4*)&As[(r0 + r) * 68 + k];
                a[r][0] = v.x; a[r][1] = v.y; a[r][2] = v.z; a[r][3] = v.w;
            }
            #pragma unroll
            for (int kk = 0; kk < 4; ++kk) {
                float4 w = *(const float4*)&Ws[((k + kk) << 6) + c0];
                #pragma unroll
                for (int r = 0; r < 4; ++r) {
                    acc[r][0] = fmaf(a[r][kk], w.x, acc[r][0]);
                    acc[r][1] = fmaf(a[r][kk], w.y, acc[r][1]);
                    acc[r][2] = fmaf(a[r][kk], w.z, acc[r][2]);
                    acc[r][3] = fmaf(a[r][kk], w.w, acc[r][3]);
                }
            }
        }
        __syncthreads();
    }

    float4 b = *(const float4*)&bias[n0 + c0];
    #pragma unroll
    for (int r = 0; r < 4; ++r) {
        int row = m0 + r0 + r;
        if (row < M) {
            float4 v;
            v.x = acc[r][0] + b.x; v.y = acc[r][1] + b.y;
            v.z = acc[r][2] + b.z; v.w = acc[r][3] + b.w;
            if (MASK_LEAKY) {
                int deg = indptr[row + 1] - indptr[row];
                if (deg == 0) {
                    v = make_float4(0.f, 0.f, 0.f, 0.f);
                } else {
                    v.x = v.x > 0.f ? v.x : 0.01f * v.x;
                    v.y = v.y > 0.f ? v.y : 0.01f * v.y;
                    v.z = v.z > 0.f ? v.z : 0.01f * v.z;
                    v.w = v.w > 0.f ? v.w : 0.01f * v.w;
                }
            }
            if (BF16_OUT) {
                uint2 w;
                w.x = bf16rne(v.x) | (bf16rne(v.y) << 16);
                w.y = bf16rne(v.z) | (bf16rne(v.w) << 16);
                *(uint2*)&((unsigned short*)Cout)[(size_t)row * N + n0 + c0] = w;
            } else {
                *(float4*)&((float*)Cout)[(size_t)row * N + n0 + c0] = v;
            }
        }
    }
}

// ---------------- launch ----------------

extern "C" void kernel_launch(void* const* d_in, const int* in_sizes, int n_in,
                              void* d_out, int out_size, void* d_ws, size_t ws_size,
                              hipStream_t stream) {
    const int*   src_cg     = (const int*)d_in[0];
    const int*   dst_cg     = (const int*)d_in[1];
    const int*   src_gc     = (const int*)d_in[2];
    const int*   dst_gc     = (const int*)d_in[3];
    const float* embed_chem = (const float*)d_in[4];
    const float* W1_cg = (const float*)d_in[6];
    const float* b1_cg = (const float*)d_in[7];
    const float* W2_gc = (const float*)d_in[12];
    const float* b2_gc = (const float*)d_in[13];
    float* out = (float*)d_out;

    // workspace layout (int words)
    int* ws_i = (int*)d_ws;
    size_t off = 0;
    int* cnt = ws_i + off; off += N_SEG;
    int* cur = ws_i + off; off += N_SEG;
    size_t zero_ints = off;
    int* bsum   = ws_i + off; off += 256;
    int* indptr = ws_i + off; off += N_SEG + 1; off = (off + 3) & ~(size_t)3;
    int* esrc   = ws_i + off; off += 2 * N_EDGES;
    float* agg1   = (float*)(ws_i + off); off += (size_t)N_GENE * IN_D;
    float* h_gene = (float*)(ws_i + off); off += (size_t)N_GENE * HID_D;
    unsigned short* Wh2b = (unsigned short*)(ws_i + off); off += (size_t)N_GENE * OUT_D / 2;
    unsigned short* embedb = (unsigned short*)(ws_i + off);
    size_t off_full = off + (size_t)N_CHEM * IN_D / 2;
    const bool bf16_embed = ws_size >= off_full * sizeof(int);   // launch-constant

    (void)hipMemsetAsync(ws_i, 0, zero_ints * sizeof(int), stream);

    const int eg2 = (2 * N_EDGES + 255) / 256;
    count_kernel<<<eg2, 256, 0, stream>>>(dst_cg, dst_gc, cnt);

    const int nb = (N_SEG + 1023) / 1024;    // 215
    block_sum_kernel<<<nb, 256, 0, stream>>>(cnt, bsum, N_SEG);
    scan_bsum_kernel<<<1, 1024, 0, stream>>>(bsum, nb);
    scan_fill_kernel<<<nb, 256, 0, stream>>>(cnt, bsum, indptr, N_SEG);
    fill_kernel<<<eg2, 256, 0, stream>>>(src_cg, dst_cg, src_gc, dst_gc, indptr, cur, esrc);

    // layer 1: aggregate raw embeddings (mean is linear; project after)
    if (bf16_embed) {
        const int n4 = N_CHEM * IN_D / 4;    // 6.4M float4s
        f32_to_bf16_kernel<<<(n4 + 255) / 256, 256, 0, stream>>>(embed_chem, embedb, n4);
        gather_mean_bf16_kernel<false><<<(N_GENE + 15) / 16, 256, 0, stream>>>(
            embedb, indptr, esrc, agg1, N_GENE);
    } else {
        gather_mean_f32_kernel<<<(N_GENE + 7) / 8, 256, 0, stream>>>(
            embed_chem, indptr, esrc, agg1, N_GENE);
    }
    // h_gene = deg>0 ? leaky(agg1 @ W1_cg + b1_cg) : 0
    {
        dim3 g((N_GENE + 63) / 64, HID_D / 64), blk(256);
        gemm_kernel<IN_D, HID_D, true, false><<<g, blk, 0, stream>>>(
            agg1, W1_cg, b1_cg, indptr, h_gene, N_GENE);
    }
    // Wh2 (bf16) = h_gene @ W2_gc + b2_gc
    {
        dim3 g((N_GENE + 63) / 64, OUT_D / 64), blk(256);
        gemm_kernel<HID_D, OUT_D, false, true><<<g, blk, 0, stream>>>(
            h_gene, W2_gc, b2_gc, nullptr, Wh2b, N_GENE);
    }
    // out = seg_mean(Wh2[src_gc], dst_gc, N_CHEM)   (chem segments start at N_GENE)
    gather_mean_bf16_kernel<true><<<(N_CHEM + 15) / 16, 256, 0, stream>>>(
        Wh2b, indptr + N_GENE, esrc, out, N_CHEM);
}